// Round 1
// baseline (667.766 us; speedup 1.0000x reference)
//
#include <hip/hip_runtime.h>

// ---------------------------------------------------------------------------
// STGCN forward, MI355X. Internal compute bf16-MFMA / fp32-accum.
// Pipeline: TC1 -> (dense-L build) -> prop GEMM x2 -> cheb combine -> TC2+stats
//           -> BN finalize. T2 never materialized (only per-node stats + t''=7 slice).
// ---------------------------------------------------------------------------

typedef __bf16 bf16;
typedef __bf16 bf16x8 __attribute__((ext_vector_type(8)));
typedef float  f32x4  __attribute__((ext_vector_type(4)));

__device__ __forceinline__ f32x4 mfma16(bf16x8 a, bf16x8 b, f32x4 c) {
  return __builtin_amdgcn_mfma_f32_16x16x32_bf16(a, b, c, 0, 0, 0);
}
__device__ __forceinline__ f32x4 splat4(float v) { f32x4 t = {v, v, v, v}; return t; }

#define NN 1024
#define EE 16384

// --------------------------- edge preprocessing ----------------------------
__global__ __launch_bounds__(256) void deg_kernel(const int* __restrict__ ei,
                                                  const float* __restrict__ ew,
                                                  float* __restrict__ deg) {
  int e = blockIdx.x * 256 + threadIdx.x;   // grid covers EE exactly
  int r = ei[e], c = ei[EE + e];
  if (r != c) atomicAdd(&deg[r], ew[e]);
}

// L[col][row] += -dinv[row]*w*dinv[col]  (dense 1024x1024 fp32)
__global__ __launch_bounds__(256) void scatterL_kernel(const int* __restrict__ ei,
                                                       const float* __restrict__ ew,
                                                       const float* __restrict__ deg,
                                                       float* __restrict__ Lf) {
  int e = blockIdx.x * 256 + threadIdx.x;
  int r = ei[e], c = ei[EE + e];
  float w = (r == c) ? 0.0f : ew[e];
  float dr = deg[r], dc = deg[c];
  float ir = dr > 0.0f ? rsqrtf(dr) : 0.0f;
  float ic = dc > 0.0f ? rsqrtf(dc) : 0.0f;
  float norm = -(ir * w * ic);
  if (norm != 0.0f) atomicAdd(&Lf[(size_t)c * NN + r], norm);
}

__global__ __launch_bounds__(256) void cvtL_kernel(const float* __restrict__ Lf,
                                                   bf16* __restrict__ Lbf) {
  int i = blockIdx.x * 256 + threadIdx.x;   // 1M exact
  Lbf[i] = (bf16)Lf[i];
}

// ------------------------------ weight prep --------------------------------
// Wc (fp32, 192x64): rows [0:64)=W0-W2, [64:128)=W1, [128:192)=2*W2
// W2c (bf16, 3 x [384][192]): W2c[conv][o][kk*64+h] = w_conv[(o*64+h)*3+kk]
__global__ __launch_bounds__(256) void wprep_kernel(const float* __restrict__ W,
                                                    const float* __restrict__ w21,
                                                    const float* __restrict__ w22,
                                                    const float* __restrict__ w23,
                                                    float* __restrict__ Wc,
                                                    bf16* __restrict__ W2c) {
  int i = blockIdx.x * 256 + threadIdx.x;   // 912*256 = 233472 = 12288 + 221184 exact
  if (i < 12288) {
    int row = i >> 6, j = i & 63;
    int src = row >> 6, h = row & 63;
    float v;
    if (src == 0)      v = W[h * 64 + j] - W[2 * 4096 + h * 64 + j];
    else if (src == 1) v = W[4096 + h * 64 + j];
    else               v = 2.0f * W[2 * 4096 + h * 64 + j];
    Wc[i] = v;
  } else {
    int j2 = i - 12288;
    int conv = j2 / 73728, rr = j2 % 73728;
    int o = rr / 192, k = rr % 192;
    int kk = k >> 6, h = k & 63;
    const float* ws = (conv == 0) ? w21 : (conv == 1) ? w22 : w23;
    W2c[j2] = (bf16)ws[(o * 64 + h) * 3 + kk];
  }
}

// ------------------------------- TC1 ---------------------------------------
// zf[(b*10+t)*64+h][n] = relu(P*sigmoid(Q)+R), feature-major bf16
__global__ __launch_bounds__(256) void tc1_kernel(const float* __restrict__ X,
                                                  const float* __restrict__ w1, const float* __restrict__ c1,
                                                  const float* __restrict__ w2, const float* __restrict__ c2,
                                                  const float* __restrict__ w3, const float* __restrict__ c3,
                                                  bf16* __restrict__ zf) {
  int row = blockIdx.y;                       // (b*10+t)*64+h, [0,10240)
  int n = blockIdx.x * 256 + threadIdx.x;
  int h = row & 63, bt = row >> 6;
  int t = bt % 10, b = bt / 10;
  float P = c1[h], Q = c2[h], R = c3[h];
  const float* xb = X + (size_t)(b * 1024 + n) * 24;   // (B,N,C=2,T=12)
  #pragma unroll
  for (int c = 0; c < 2; c++)
    #pragma unroll
    for (int k = 0; k < 3; k++) {
      float xv = xb[c * 12 + t + k];
      int wi = (h * 2 + c) * 3 + k;
      P += xv * w1[wi]; Q += xv * w2[wi]; R += xv * w3[wi];
    }
  float Hv = P * (1.0f / (1.0f + __expf(-Q))) + R;
  Hv = Hv > 0.0f ? Hv : 0.0f;
  zf[(size_t)row * NN + n] = (bf16)Hv;
}

// --------------------------- B^T GEMM (bf16) -------------------------------
// C[M][Nc] = A[M][K] * Bt[Nc][K]^T ; tiles 128x128, BK=64, 4 waves
__global__ __launch_bounds__(256) void gemm_bt(const bf16* __restrict__ A,
                                               const bf16* __restrict__ Bt,
                                               bf16* __restrict__ C,
                                               int M, int Nc, int K) {
  __shared__ __align__(16) bf16 As[128 * 72];
  __shared__ __align__(16) bf16 Bs[128 * 72];
  const int tid = threadIdx.x, lane = tid & 63, w = tid >> 6;
  const int wm = w >> 1, wn = w & 1;
  const int m0 = blockIdx.y * 128, n0 = blockIdx.x * 128;
  const int colL = lane & 15, kg = lane >> 4;

  f32x4 acc[4][4];
  #pragma unroll
  for (int i = 0; i < 4; i++)
    #pragma unroll
    for (int j = 0; j < 4; j++) acc[i][j] = splat4(0.0f);

  for (int kb = 0; kb < K; kb += 64) {
    __syncthreads();
    #pragma unroll
    for (int i = 0; i < 4; i++) {
      int idx = i * 256 + tid;
      int row = idx >> 3, ch = idx & 7;
      *(bf16x8*)(&As[row * 72 + ch * 8]) =
          *(const bf16x8*)(&A[(size_t)(m0 + row) * K + kb + ch * 8]);
      *(bf16x8*)(&Bs[row * 72 + ch * 8]) =
          *(const bf16x8*)(&Bt[(size_t)(n0 + row) * K + kb + ch * 8]);
    }
    __syncthreads();
    #pragma unroll
    for (int kk = 0; kk < 2; kk++) {
      int krow = kk * 32 + kg * 8;
      bf16x8 af[4], bfr[4];
      #pragma unroll
      for (int mt = 0; mt < 4; mt++)
        af[mt] = *(const bf16x8*)(&As[(wm * 64 + mt * 16 + colL) * 72 + krow]);
      #pragma unroll
      for (int nt = 0; nt < 4; nt++)
        bfr[nt] = *(const bf16x8*)(&Bs[(wn * 64 + nt * 16 + colL) * 72 + krow]);
      #pragma unroll
      for (int mt = 0; mt < 4; mt++)
        #pragma unroll
        for (int nt = 0; nt < 4; nt++)
          acc[mt][nt] = mfma16(af[mt], bfr[nt], acc[mt][nt]);
    }
  }
  // store: C/D layout col=lane&15, row=(lane>>4)*4+r
  #pragma unroll
  for (int mt = 0; mt < 4; mt++)
    #pragma unroll
    for (int nt = 0; nt < 4; nt++) {
      int m = m0 + wm * 64 + mt * 16 + kg * 4;
      int n = n0 + wn * 64 + nt * 16 + colL;
      #pragma unroll
      for (int r = 0; r < 4; r++)
        C[(size_t)(m + r) * Nc + n] = (bf16)acc[mt][nt][r];
    }
}

// ------------------------- cheb combine (vector) ---------------------------
// Tg[n][b][t][h'] = relu(cheb_b[h'] + sum_h z*Wc[0:64] + P1*Wc[64:128] + P2*Wc[128:192])
__global__ __launch_bounds__(256) void combine_kernel(const bf16* __restrict__ zf,
                                                      const bf16* __restrict__ P1f,
                                                      const bf16* __restrict__ P2f,
                                                      const float* __restrict__ Wc,
                                                      const float* __restrict__ chebb,
                                                      bf16* __restrict__ Tg) {
  int slab = blockIdx.y;                       // bt in [0,160)
  int n = blockIdx.x * 256 + threadIdx.x;
  int b = slab / 10, t = slab % 10;
  float acc[64];
  #pragma unroll
  for (int j = 0; j < 64; j++) acc[j] = chebb[j];
  #pragma unroll 1
  for (int src = 0; src < 3; src++) {
    const bf16* Z = (src == 0) ? zf : (src == 1) ? P1f : P2f;
    for (int h = 0; h < 64; h++) {
      float v = (float)Z[(size_t)(slab * 64 + h) * NN + n];
      const float* wr = Wc + (src * 64 + h) * 64;   // uniform -> s_loads
      #pragma unroll
      for (int j = 0; j < 64; j++) acc[j] += v * wr[j];
    }
  }
  size_t base = (size_t)((n * 16 + b) * 10 + t) * 64;
  #pragma unroll
  for (int j = 0; j < 64; j++) {
    float x = acc[j];
    Tg[base + j] = (bf16)(x > 0.0f ? x : 0.0f);
  }
}

// ----------------------- TC2 + fused BN stats ------------------------------
// block = 128 nodes at fixed (b,t''); A = Tg windows staged in LDS (padded);
// 3 weight mats (P/Q/R) share A-frag -> lane-local GLU epilogue; stats fused.
__global__ __launch_bounds__(256) void tc2_kernel(const bf16* __restrict__ Tg,
                                                  const bf16* __restrict__ W2c,
                                                  const float* __restrict__ b1,
                                                  const float* __restrict__ b2,
                                                  const float* __restrict__ b3,
                                                  float* __restrict__ nsum,
                                                  float* __restrict__ nsq,
                                                  bf16* __restrict__ slice) {
  __shared__ __align__(16) bf16 As[128 * 200];   // 192 + pad 8 -> 2-way-free banks
  const int rb = blockIdx.x;                     // 1024 blocks
  const int bt = rb >> 3, ncb = rb & 7;
  const int b = bt >> 3, tpp = bt & 7;
  const int n0 = ncb << 7;
  const int tid = threadIdx.x, lane = tid & 63, w = tid >> 6;
  const int colL = lane & 15, kg = lane >> 4;

  #pragma unroll
  for (int i = 0; i < 12; i++) {
    int idx = i * 256 + tid;
    int row = idx / 24, ch = idx % 24;
    *(bf16x8*)(&As[row * 200 + ch * 8]) =
        *(const bf16x8*)(&Tg[(size_t)((n0 + row) * 16 + b) * 640 + tpp * 64 + ch * 8]);
  }
  __syncthreads();

  float ssum[2][4] = {{0, 0, 0, 0}, {0, 0, 0, 0}};
  float ssq[2][4]  = {{0, 0, 0, 0}, {0, 0, 0, 0}};

  #pragma unroll 1
  for (int ch = 0; ch < 6; ch++) {               // 64-o chunks
    f32x4 aP[2][4], aQ[2][4], aR[2][4];
    #pragma unroll
    for (int ot = 0; ot < 4; ot++) {
      int o = ch * 64 + ot * 16 + colL;
      float v1 = b1[o], v2 = b2[o], v3 = b3[o];
      #pragma unroll
      for (int mt = 0; mt < 2; mt++) {
        aP[mt][ot] = splat4(v1); aQ[mt][ot] = splat4(v2); aR[mt][ot] = splat4(v3);
      }
    }
    #pragma unroll
    for (int ks = 0; ks < 6; ks++) {
      bf16x8 a0 = *(const bf16x8*)(&As[(w * 32 + colL) * 200 + ks * 32 + kg * 8]);
      bf16x8 a1 = *(const bf16x8*)(&As[(w * 32 + 16 + colL) * 200 + ks * 32 + kg * 8]);
      #pragma unroll
      for (int ot = 0; ot < 4; ot++) {
        int o = ch * 64 + ot * 16 + colL;
        size_t wb = (size_t)o * 192 + ks * 32 + kg * 8;
        bf16x8 bP = *(const bf16x8*)(&W2c[wb]);
        bf16x8 bQ = *(const bf16x8*)(&W2c[73728 + wb]);
        bf16x8 bR = *(const bf16x8*)(&W2c[147456 + wb]);
        aP[0][ot] = mfma16(a0, bP, aP[0][ot]);
        aP[1][ot] = mfma16(a1, bP, aP[1][ot]);
        aQ[0][ot] = mfma16(a0, bQ, aQ[0][ot]);
        aQ[1][ot] = mfma16(a1, bQ, aQ[1][ot]);
        aR[0][ot] = mfma16(a0, bR, aR[0][ot]);
        aR[1][ot] = mfma16(a1, bR, aR[1][ot]);
      }
    }
    #pragma unroll
    for (int mt = 0; mt < 2; mt++)
      #pragma unroll
      for (int ot = 0; ot < 4; ot++) {
        int o = ch * 64 + ot * 16 + colL;
        #pragma unroll
        for (int r = 0; r < 4; r++) {
          float p = aP[mt][ot][r], q = aQ[mt][ot][r], rr = aR[mt][ot][r];
          float h = p * (1.0f / (1.0f + __expf(-q))) + rr;
          h = h > 0.0f ? h : 0.0f;
          ssum[mt][r] += h;
          ssq[mt][r] += h * h;
          if (tpp == 7) {
            int n = n0 + w * 32 + mt * 16 + kg * 4 + r;
            slice[(size_t)((b << 10) + n) * 384 + o] = (bf16)h;
          }
        }
      }
  }
  // reduce 16 cols per row via shfl butterfly, then 2 atomics/row
  #pragma unroll
  for (int mt = 0; mt < 2; mt++)
    #pragma unroll
    for (int r = 0; r < 4; r++) {
      float s = ssum[mt][r], q = ssq[mt][r];
      #pragma unroll
      for (int d = 1; d < 16; d <<= 1) {
        s += __shfl_xor(s, d);
        q += __shfl_xor(q, d);
      }
      if (colL == 0) {
        int n = n0 + w * 32 + mt * 16 + kg * 4 + r;
        atomicAdd(&nsum[n], s);
        atomicAdd(&nsq[n], q);
      }
    }
}

// ----------------------------- BN finalize ---------------------------------
__global__ __launch_bounds__(256) void bnstat_kernel(const float* __restrict__ nsum,
                                                     const float* __restrict__ nsq,
                                                     const float* __restrict__ gamma,
                                                     const float* __restrict__ beta,
                                                     float* __restrict__ scoff) {
  int n = blockIdx.x * 256 + threadIdx.x;       // 1024 exact
  const float inv_cnt = 1.0f / 49152.0f;        // B*8*384
  float m = nsum[n] * inv_cnt;
  float var = nsq[n] * inv_cnt - m * m;
  float sc = rsqrtf(var + 1e-5f) * gamma[n];
  scoff[n] = sc;
  scoff[1024 + n] = beta[n] - m * sc;
}

// out[f], f = c*16384 + b*1024 + n  (== reshape(T,B,N,OUT) flat order)
__global__ __launch_bounds__(256) void final_kernel(const bf16* __restrict__ slice,
                                                    const float* __restrict__ scoff,
                                                    float* __restrict__ out) {
  int f = blockIdx.x * 256 + threadIdx.x;       // 6291456 exact
  int c = f >> 14, rem = f & 16383;
  int b = rem >> 10, n = rem & 1023;
  out[f] = (float)slice[(size_t)((b << 10) + n) * 384 + c] * scoff[n] + scoff[1024 + n];
}

// ---------------------------------------------------------------------------
extern "C" void kernel_launch(void* const* d_in, const int* in_sizes, int n_in,
                              void* d_out, int out_size, void* d_ws, size_t ws_size,
                              hipStream_t stream) {
  const float* X    = (const float*)d_in[0];
  const int*   ei   = (const int*)d_in[1];
  const float* ew   = (const float*)d_in[2];
  const float* t1w1 = (const float*)d_in[3];
  const float* t1b1 = (const float*)d_in[4];
  const float* t1w2 = (const float*)d_in[5];
  const float* t1b2 = (const float*)d_in[6];
  const float* t1w3 = (const float*)d_in[7];
  const float* t1b3 = (const float*)d_in[8];
  const float* chebW = (const float*)d_in[9];
  const float* chebB = (const float*)d_in[10];
  const float* t2w1 = (const float*)d_in[11];
  const float* t2b1 = (const float*)d_in[12];
  const float* t2w2 = (const float*)d_in[13];
  const float* t2b2 = (const float*)d_in[14];
  const float* t2w3 = (const float*)d_in[15];
  const float* t2b3 = (const float*)d_in[16];
  const float* gamma = (const float*)d_in[17];
  const float* beta  = (const float*)d_in[18];
  float* out = (float*)d_out;

  char* ws = (char*)d_ws;
  float* Lf    = (float*)(ws);                  // 4 MB dense L (fp32 scatter target)
  float* deg   = (float*)(ws + 4194304);
  float* nsum  = (float*)(ws + 4198400);
  float* nsq   = (float*)(ws + 4202496);
  bf16*  Lbf   = (bf16*)(ws + 4210688);         // 2 MB
  bf16*  zf    = (bf16*)(ws + 6307840);         // 20 MB feature-major z
  bf16*  P1f   = (bf16*)(ws + 27279360);        // 20 MB
  bf16*  P2f   = (bf16*)(ws + 48250880);        // 20 MB
  bf16*  Tg    = (bf16*)(ws + 69222400);        // 20 MB node-major
  float* Wc    = (float*)(ws + 90193920);       // 48 KB combined cheb weights
  bf16*  W2c   = (bf16*)(ws + 90243072);        // 432 KB tc2 weights [conv][o][k]
  bf16*  slice = (bf16*)(ws + 90685440);        // 12 MB t''=7 slice
  float* scoff = (float*)(ws + 103268352);      // 8 KB

  hipMemsetAsync(ws, 0, 4206592, stream);       // Lf + deg + nsum + nsq

  wprep_kernel<<<912, 256, 0, stream>>>(chebW, t2w1, t2w2, t2w3, Wc, W2c);
  tc1_kernel<<<dim3(4, 10240), 256, 0, stream>>>(X, t1w1, t1b1, t1w2, t1b2, t1w3, t1b3, zf);
  deg_kernel<<<64, 256, 0, stream>>>(ei, ew, deg);
  scatterL_kernel<<<64, 256, 0, stream>>>(ei, ew, deg, Lf);
  cvtL_kernel<<<4096, 256, 0, stream>>>(Lf, Lbf);
  gemm_bt<<<dim3(8, 80), 256, 0, stream>>>(zf, Lbf, P1f, 10240, 1024, 1024);
  gemm_bt<<<dim3(8, 80), 256, 0, stream>>>(P1f, Lbf, P2f, 10240, 1024, 1024);
  combine_kernel<<<dim3(4, 160), 256, 0, stream>>>(zf, P1f, P2f, Wc, chebB, Tg);
  tc2_kernel<<<1024, 256, 0, stream>>>(Tg, W2c, t2b1, t2b2, t2b3, nsum, nsq, slice);
  bnstat_kernel<<<4, 256, 0, stream>>>(nsum, nsq, gamma, beta, scoff);
  final_kernel<<<24576, 256, 0, stream>>>(slice, scoff, out);
}

// Round 2
// 547.498 us; speedup vs baseline: 1.2197x; 1.2197x over previous
//
#include <hip/hip_runtime.h>

// ---------------------------------------------------------------------------
// STGCN forward, MI355X. Internal compute bf16-MFMA / fp32-accum.
// TC1 -> (dense-L build) -> prop GEMM x2 -> cheb combine -> TC2-as-GEMM+stats
// -> BN finalize. T2 never materialized (only per-node stats + t''=7 slice).
// ---------------------------------------------------------------------------

typedef __bf16 bf16;
typedef __bf16 bf16x8 __attribute__((ext_vector_type(8)));
typedef float  f32x4  __attribute__((ext_vector_type(4)));

__device__ __forceinline__ f32x4 mfma16(bf16x8 a, bf16x8 b, f32x4 c) {
  return __builtin_amdgcn_mfma_f32_16x16x32_bf16(a, b, c, 0, 0, 0);
}
__device__ __forceinline__ f32x4 splat4(float v) { f32x4 t = {v, v, v, v}; return t; }

// async global->LDS, 16B per lane; lds base must be wave-uniform (lane*16 auto)
__device__ __forceinline__ void lds_load16(const bf16* g, bf16* l) {
  __builtin_amdgcn_global_load_lds((const __attribute__((address_space(1))) void*)g,
                                   (__attribute__((address_space(3))) void*)l, 16, 0, 0);
}

#define NN 1024
#define EE 16384

// --------------------------- edge preprocessing ----------------------------
__global__ __launch_bounds__(256) void deg_kernel(const int* __restrict__ ei,
                                                  const float* __restrict__ ew,
                                                  float* __restrict__ deg) {
  int e = blockIdx.x * 256 + threadIdx.x;
  int r = ei[e], c = ei[EE + e];
  if (r != c) atomicAdd(&deg[r], ew[e]);
}

// L[col][row] += -dinv[row]*w*dinv[col]  (dense 1024x1024 fp32)
__global__ __launch_bounds__(256) void scatterL_kernel(const int* __restrict__ ei,
                                                       const float* __restrict__ ew,
                                                       const float* __restrict__ deg,
                                                       float* __restrict__ Lf) {
  int e = blockIdx.x * 256 + threadIdx.x;
  int r = ei[e], c = ei[EE + e];
  float w = (r == c) ? 0.0f : ew[e];
  float dr = deg[r], dc = deg[c];
  float ir = dr > 0.0f ? rsqrtf(dr) : 0.0f;
  float ic = dc > 0.0f ? rsqrtf(dc) : 0.0f;
  float norm = -(ir * w * ic);
  if (norm != 0.0f) atomicAdd(&Lf[(size_t)c * NN + r], norm);
}

__global__ __launch_bounds__(256) void cvtL_kernel(const float* __restrict__ Lf,
                                                   bf16* __restrict__ Lbf) {
  int i = blockIdx.x * 256 + threadIdx.x;
  Lbf[i] = (bf16)Lf[i];
}

// ------------------------------ weight prep --------------------------------
// Wc (fp32, 192x64): rows [0:64)=W0-W2, [64:128)=W1, [128:192)=2*W2
// W2c (bf16, [1152 cols][192 k]): col = og*48 + conv*16 + oo  (o = og*16+oo)
//   k = kk*64 + h ; value = w_conv[(o*64+h)*3 + kk]
__global__ __launch_bounds__(256) void wprep_kernel(const float* __restrict__ W,
                                                    const float* __restrict__ w21,
                                                    const float* __restrict__ w22,
                                                    const float* __restrict__ w23,
                                                    float* __restrict__ Wc,
                                                    bf16* __restrict__ W2c) {
  int i = blockIdx.x * 256 + threadIdx.x;   // 912*256 = 233472 = 12288 + 221184 exact
  if (i < 12288) {
    int row = i >> 6, j = i & 63;
    int src = row >> 6, h = row & 63;
    float v;
    if (src == 0)      v = W[h * 64 + j] - W[2 * 4096 + h * 64 + j];
    else if (src == 1) v = W[4096 + h * 64 + j];
    else               v = 2.0f * W[2 * 4096 + h * 64 + j];
    Wc[i] = v;
  } else {
    int j2 = i - 12288;                      // [0, 221184)
    int c = j2 / 192, k = j2 % 192;
    int og = c / 48, r48 = c % 48;
    int conv = r48 >> 4, oo = r48 & 15;
    int o = og * 16 + oo;
    int kk = k >> 6, h = k & 63;
    const float* ws = (conv == 0) ? w21 : (conv == 1) ? w22 : w23;
    W2c[j2] = (bf16)ws[(o * 64 + h) * 3 + kk];
  }
}

// ------------------------------- TC1 ---------------------------------------
// zf[(b*10+t)*64+h][n] = relu(P*sigmoid(Q)+R), feature-major bf16
__global__ __launch_bounds__(256) void tc1_kernel(const float* __restrict__ X,
                                                  const float* __restrict__ w1, const float* __restrict__ c1,
                                                  const float* __restrict__ w2, const float* __restrict__ c2,
                                                  const float* __restrict__ w3, const float* __restrict__ c3,
                                                  bf16* __restrict__ zf) {
  int row = blockIdx.y;                       // (b*10+t)*64+h, [0,10240)
  int n = blockIdx.x * 256 + threadIdx.x;
  int h = row & 63, bt = row >> 6;
  int t = bt % 10, b = bt / 10;
  float P = c1[h], Q = c2[h], R = c3[h];
  const float* xb = X + (size_t)(b * 1024 + n) * 24;   // (B,N,C=2,T=12)
  #pragma unroll
  for (int c = 0; c < 2; c++)
    #pragma unroll
    for (int k = 0; k < 3; k++) {
      float xv = xb[c * 12 + t + k];
      int wi = (h * 2 + c) * 3 + k;
      P += xv * w1[wi]; Q += xv * w2[wi]; R += xv * w3[wi];
    }
  float Hv = P * (1.0f / (1.0f + __expf(-Q))) + R;
  Hv = Hv > 0.0f ? Hv : 0.0f;
  zf[(size_t)row * NN + n] = (bf16)Hv;
}

// --------------------------- B^T GEMM (bf16) -------------------------------
// C[M][Nc] = A[M][K] * Bt[Nc][K]^T ; 128x128 tile, BK=64, global_load_lds
__global__ __launch_bounds__(256) void gemm_bt(const bf16* __restrict__ A,
                                               const bf16* __restrict__ Bt,
                                               bf16* __restrict__ C,
                                               int M, int Nc, int K) {
  __shared__ __align__(16) bf16 As[8192];
  __shared__ __align__(16) bf16 Bs[8192];
  const int tid = threadIdx.x, lane = tid & 63, w = tid >> 6;
  const int wm = w >> 1, wn = w & 1;
  const int m0 = blockIdx.y * 128, n0 = blockIdx.x * 128;
  const int colL = lane & 15, kg = lane >> 4;

  f32x4 acc[4][4];
  #pragma unroll
  for (int i = 0; i < 4; i++)
    #pragma unroll
    for (int j = 0; j < 4; j++) acc[i][j] = splat4(0.0f);

  for (int kb = 0; kb < K; kb += 64) {
    if (kb) __syncthreads();
    #pragma unroll
    for (int i = 0; i < 4; i++) {
      int e = (w * 4 + i) * 512 + lane * 8;
      int row = e >> 6, k = e & 63;
      lds_load16(&A[(size_t)(m0 + row) * K + kb + k], &As[(w * 4 + i) * 512]);
      lds_load16(&Bt[(size_t)(n0 + row) * K + kb + k], &Bs[(w * 4 + i) * 512]);
    }
    __syncthreads();
    #pragma unroll
    for (int kk = 0; kk < 2; kk++) {
      bf16x8 af[4], bfr[4];
      #pragma unroll
      for (int mt = 0; mt < 4; mt++)
        af[mt] = *(const bf16x8*)(&As[(wm * 64 + mt * 16 + colL) * 64 + kk * 32 + kg * 8]);
      #pragma unroll
      for (int nt = 0; nt < 4; nt++)
        bfr[nt] = *(const bf16x8*)(&Bs[(wn * 64 + nt * 16 + colL) * 64 + kk * 32 + kg * 8]);
      #pragma unroll
      for (int mt = 0; mt < 4; mt++)
        #pragma unroll
        for (int nt = 0; nt < 4; nt++)
          acc[mt][nt] = mfma16(af[mt], bfr[nt], acc[mt][nt]);
    }
  }
  #pragma unroll
  for (int mt = 0; mt < 4; mt++)
    #pragma unroll
    for (int nt = 0; nt < 4; nt++) {
      int m = m0 + wm * 64 + mt * 16 + kg * 4;
      int n = n0 + wn * 64 + nt * 16 + colL;
      #pragma unroll
      for (int r = 0; r < 4; r++)
        C[(size_t)(m + r) * Nc + n] = (bf16)acc[mt][nt][r];
    }
}

// ------------------------- cheb combine (vector) ---------------------------
// Tg[n][b][t][h'] = relu(cheb_b[h'] + sum_h z*Wc[0:64] + P1*Wc[64:128] + P2*Wc[128:192])
__global__ __launch_bounds__(256) void combine_kernel(const bf16* __restrict__ zf,
                                                      const bf16* __restrict__ P1f,
                                                      const bf16* __restrict__ P2f,
                                                      const float* __restrict__ Wc,
                                                      const float* __restrict__ chebb,
                                                      bf16* __restrict__ Tg) {
  int slab = blockIdx.y;                       // bt in [0,160)
  int n = blockIdx.x * 256 + threadIdx.x;
  int b = slab / 10, t = slab % 10;
  float acc[64];
  #pragma unroll
  for (int j = 0; j < 64; j++) acc[j] = chebb[j];
  #pragma unroll 1
  for (int src = 0; src < 3; src++) {
    const bf16* Z = (src == 0) ? zf : (src == 1) ? P1f : P2f;
    for (int h = 0; h < 64; h++) {
      float v = (float)Z[(size_t)(slab * 64 + h) * NN + n];
      const float* wr = Wc + (src * 64 + h) * 64;   // uniform -> s_loads
      #pragma unroll
      for (int j = 0; j < 64; j++) acc[j] += v * wr[j];
    }
  }
  size_t base = (size_t)((n * 16 + b) * 10 + t) * 64;
  #pragma unroll
  for (int j = 0; j < 64; j++) {
    float x = acc[j];
    Tg[base + j] = (bf16)(x > 0.0f ? x : 0.0f);
  }
}

// ----------------------- TC2 as GEMM + fused BN stats ----------------------
// C[131072 x 1152] = TgWin[131072 x 192] * W2c^T, BM=128, BN=192, BK=64.
// Col layout og*48+conv*16+oo => GLU triple (P,Q,R) is lane-local across
// three adjacent 16-col tiles. 4 waves, each 64 rows x 96 cols.
// blockIdx.x = rb (b,tpp,n-chunk), blockIdx.y = cho (4 o-groups each).
__global__ __launch_bounds__(256) void tc2_kernel(const bf16* __restrict__ Tg,
                                                  const bf16* __restrict__ W2c,
                                                  const float* __restrict__ b1,
                                                  const float* __restrict__ b2,
                                                  const float* __restrict__ b3,
                                                  float* __restrict__ nsum,
                                                  float* __restrict__ nsq,
                                                  bf16* __restrict__ slice) {
  __shared__ __align__(16) char smem[40960];
  bf16* As = (bf16*)smem;                 // [128][64]  16 KB
  bf16* Ws = (bf16*)(smem + 16384);       // [192][64]  24 KB
  const int rb = blockIdx.x, cho = blockIdx.y;
  const int b = rb >> 6, tpp = (rb >> 3) & 7, n0 = (rb & 7) << 7;
  const int tid = threadIdx.x, lane = tid & 63, w = tid >> 6;
  const int wm = w >> 1, wn = w & 1;
  const int colL = lane & 15, kg = lane >> 4;

  f32x4 acc[4][6];
  #pragma unroll
  for (int i = 0; i < 4; i++)
    #pragma unroll
    for (int j = 0; j < 6; j++) acc[i][j] = splat4(0.0f);

  for (int kb = 0; kb < 192; kb += 64) {
    if (kb) __syncthreads();
    #pragma unroll
    for (int i = 0; i < 4; i++) {          // A: 128x64
      int e = (w * 4 + i) * 512 + lane * 8;
      int row = e >> 6, k = e & 63;
      lds_load16(&Tg[(size_t)((n0 + row) * 16 + b) * 640 + tpp * 64 + kb + k],
                 &As[(w * 4 + i) * 512]);
    }
    #pragma unroll
    for (int i = 0; i < 6; i++) {          // W: 192x64
      int e = (w * 6 + i) * 512 + lane * 8;
      int col = e >> 6, k = e & 63;
      lds_load16(&W2c[(size_t)(cho * 192 + col) * 192 + kb + k],
                 &Ws[(w * 6 + i) * 512]);
    }
    __syncthreads();
    #pragma unroll
    for (int kk = 0; kk < 2; kk++) {
      bf16x8 af[4], bfr[6];
      #pragma unroll
      for (int mt = 0; mt < 4; mt++)
        af[mt] = *(const bf16x8*)(&As[(wm * 64 + mt * 16 + colL) * 64 + kk * 32 + kg * 8]);
      #pragma unroll
      for (int j = 0; j < 6; j++)
        bfr[j] = *(const bf16x8*)(&Ws[(wn * 96 + j * 16 + colL) * 64 + kk * 32 + kg * 8]);
      #pragma unroll
      for (int mt = 0; mt < 4; mt++)
        #pragma unroll
        for (int j = 0; j < 6; j++)
          acc[mt][j] = mfma16(af[mt], bfr[j], acc[mt][j]);
    }
  }

  // GLU epilogue + per-row stats
  float ssum[4][4], ssq[4][4];
  #pragma unroll
  for (int mt = 0; mt < 4; mt++)
    #pragma unroll
    for (int r = 0; r < 4; r++) { ssum[mt][r] = 0.0f; ssq[mt][r] = 0.0f; }

  float bv1[2], bv2[2], bv3[2];
  int obase[2];
  #pragma unroll
  for (int g = 0; g < 2; g++) {
    int o = ((cho * 4 + wn * 2 + g) << 4) + colL;
    obase[g] = o;
    bv1[g] = b1[o]; bv2[g] = b2[o]; bv3[g] = b3[o];
  }

  #pragma unroll
  for (int mt = 0; mt < 4; mt++)
    #pragma unroll
    for (int g = 0; g < 2; g++) {
      int o = obase[g];
      #pragma unroll
      for (int r = 0; r < 4; r++) {
        float p  = acc[mt][g * 3 + 0][r] + bv1[g];
        float q  = acc[mt][g * 3 + 1][r] + bv2[g];
        float rr = acc[mt][g * 3 + 2][r] + bv3[g];
        float h = p * (1.0f / (1.0f + __expf(-q))) + rr;
        h = h > 0.0f ? h : 0.0f;
        ssum[mt][r] += h;
        ssq[mt][r] += h * h;
        if (tpp == 7) {
          int n = n0 + wm * 64 + mt * 16 + kg * 4 + r;
          slice[(size_t)((b << 10) + n) * 384 + o] = (bf16)h;
        }
      }
    }

  // reduce over colL (16 lanes), then LDS, then 2 atomics per row
  __syncthreads();                          // all LDS reads done; alias smem
  float* sred = (float*)smem;               // [128][2]
  if (tid < 256) { sred[tid] = 0.0f; }
  __syncthreads();
  #pragma unroll
  for (int mt = 0; mt < 4; mt++)
    #pragma unroll
    for (int r = 0; r < 4; r++) {
      float s = ssum[mt][r], q = ssq[mt][r];
      #pragma unroll
      for (int d = 1; d < 16; d <<= 1) {
        s += __shfl_xor(s, d);
        q += __shfl_xor(q, d);
      }
      if (colL == 0) {
        int rl = wm * 64 + mt * 16 + kg * 4 + r;   // local row [0,128)
        atomicAdd(&sred[rl * 2], s);
        atomicAdd(&sred[rl * 2 + 1], q);
      }
    }
  __syncthreads();
  if (tid < 128) {
    atomicAdd(&nsum[n0 + tid], sred[tid * 2]);
    atomicAdd(&nsq[n0 + tid], sred[tid * 2 + 1]);
  }
}

// ----------------------------- BN finalize ---------------------------------
__global__ __launch_bounds__(256) void bnstat_kernel(const float* __restrict__ nsum,
                                                     const float* __restrict__ nsq,
                                                     const float* __restrict__ gamma,
                                                     const float* __restrict__ beta,
                                                     float* __restrict__ scoff) {
  int n = blockIdx.x * 256 + threadIdx.x;       // 1024 exact
  const float inv_cnt = 1.0f / 49152.0f;        // B*8*384
  float m = nsum[n] * inv_cnt;
  float var = nsq[n] * inv_cnt - m * m;
  float sc = rsqrtf(var + 1e-5f) * gamma[n];
  scoff[n] = sc;
  scoff[1024 + n] = beta[n] - m * sc;
}

// out[f], f = c*16384 + b*1024 + n  (== reshape(T,B,N,OUT) flat order)
__global__ __launch_bounds__(256) void final_kernel(const bf16* __restrict__ slice,
                                                    const float* __restrict__ scoff,
                                                    float* __restrict__ out) {
  int f = blockIdx.x * 256 + threadIdx.x;       // 6291456 exact
  int c = f >> 14, rem = f & 16383;
  int b = rem >> 10, n = rem & 1023;
  out[f] = (float)slice[(size_t)((b << 10) + n) * 384 + c] * scoff[n] + scoff[1024 + n];
}

// ---------------------------------------------------------------------------
extern "C" void kernel_launch(void* const* d_in, const int* in_sizes, int n_in,
                              void* d_out, int out_size, void* d_ws, size_t ws_size,
                              hipStream_t stream) {
  const float* X    = (const float*)d_in[0];
  const int*   ei   = (const int*)d_in[1];
  const float* ew   = (const float*)d_in[2];
  const float* t1w1 = (const float*)d_in[3];
  const float* t1b1 = (const float*)d_in[4];
  const float* t1w2 = (const float*)d_in[5];
  const float* t1b2 = (const float*)d_in[6];
  const float* t1w3 = (const float*)d_in[7];
  const float* t1b3 = (const float*)d_in[8];
  const float* chebW = (const float*)d_in[9];
  const float* chebB = (const float*)d_in[10];
  const float* t2w1 = (const float*)d_in[11];
  const float* t2b1 = (const float*)d_in[12];
  const float* t2w2 = (const float*)d_in[13];
  const float* t2b2 = (const float*)d_in[14];
  const float* t2w3 = (const float*)d_in[15];
  const float* t2b3 = (const float*)d_in[16];
  const float* gamma = (const float*)d_in[17];
  const float* beta  = (const float*)d_in[18];
  float* out = (float*)d_out;

  char* ws = (char*)d_ws;
  float* Lf    = (float*)(ws);                  // 4 MB dense L (fp32 scatter target)
  float* deg   = (float*)(ws + 4194304);
  float* nsum  = (float*)(ws + 4198400);
  float* nsq   = (float*)(ws + 4202496);
  bf16*  Lbf   = (bf16*)(ws + 4210688);         // 2 MB
  bf16*  zf    = (bf16*)(ws + 6307840);         // 20 MB feature-major z
  bf16*  P1f   = (bf16*)(ws + 27279360);        // 20 MB
  bf16*  P2f   = (bf16*)(ws + 48250880);        // 20 MB
  bf16*  Tg    = (bf16*)(ws + 69222400);        // 20 MB node-major
  float* Wc    = (float*)(ws + 90193920);       // 48 KB combined cheb weights
  bf16*  W2c   = (bf16*)(ws + 90243072);        // 432 KB tc2 weights [col][k]
  bf16*  slice = (bf16*)(ws + 90685440);        // 12 MB t''=7 slice
  float* scoff = (float*)(ws + 103268352);      // 8 KB

  hipMemsetAsync(ws, 0, 4206592, stream);       // Lf + deg + nsum + nsq

  wprep_kernel<<<912, 256, 0, stream>>>(chebW, t2w1, t2w2, t2w3, Wc, W2c);
  tc1_kernel<<<dim3(4, 10240), 256, 0, stream>>>(X, t1w1, t1b1, t1w2, t1b2, t1w3, t1b3, zf);
  deg_kernel<<<64, 256, 0, stream>>>(ei, ew, deg);
  scatterL_kernel<<<64, 256, 0, stream>>>(ei, ew, deg, Lf);
  cvtL_kernel<<<4096, 256, 0, stream>>>(Lf, Lbf);
  gemm_bt<<<dim3(8, 80), 256, 0, stream>>>(zf, Lbf, P1f, 10240, 1024, 1024);
  gemm_bt<<<dim3(8, 80), 256, 0, stream>>>(P1f, Lbf, P2f, 10240, 1024, 1024);
  combine_kernel<<<dim3(4, 160), 256, 0, stream>>>(zf, P1f, P2f, Wc, chebB, Tg);
  tc2_kernel<<<dim3(1024, 6), 256, 0, stream>>>(Tg, W2c, t2b1, t2b2, t2b3, nsum, nsq, slice);
  bnstat_kernel<<<4, 256, 0, stream>>>(nsum, nsq, gamma, beta, scoff);
  final_kernel<<<24576, 256, 0, stream>>>(slice, scoff, out);
}

// Round 3
// 417.290 us; speedup vs baseline: 1.6002x; 1.3120x over previous
//
#include <hip/hip_runtime.h>

// ---------------------------------------------------------------------------
// STGCN forward, MI355X. Internal compute bf16-MFMA / fp32-accum.
// TC1 -> (dense-L build) -> prop GEMM x2 -> cheb combine -> TC2-as-GEMM+stats
// -> BN finalize. T2 never materialized (only per-node stats + t''=7 slice).
// ---------------------------------------------------------------------------

typedef __bf16 bf16;
typedef __bf16 bf16x8 __attribute__((ext_vector_type(8)));
typedef float  f32x4  __attribute__((ext_vector_type(4)));

__device__ __forceinline__ f32x4 mfma16(bf16x8 a, bf16x8 b, f32x4 c) {
  return __builtin_amdgcn_mfma_f32_16x16x32_bf16(a, b, c, 0, 0, 0);
}
__device__ __forceinline__ f32x4 splat4(float v) { f32x4 t = {v, v, v, v}; return t; }

// async global->LDS, 16B per lane; lds base must be wave-uniform (lane*16 auto)
__device__ __forceinline__ void lds_load16(const bf16* g, bf16* l) {
  __builtin_amdgcn_global_load_lds((const __attribute__((address_space(1))) void*)g,
                                   (__attribute__((address_space(3))) void*)l, 16, 0, 0);
}

#define NN 1024
#define EE 16384

// --------------------------- edge preprocessing ----------------------------
__global__ __launch_bounds__(256) void deg_kernel(const int* __restrict__ ei,
                                                  const float* __restrict__ ew,
                                                  float* __restrict__ deg) {
  int e = blockIdx.x * 256 + threadIdx.x;
  int r = ei[e], c = ei[EE + e];
  if (r != c) atomicAdd(&deg[r], ew[e]);
}

// L[col][row] += -dinv[row]*w*dinv[col]  (dense 1024x1024 fp32)
__global__ __launch_bounds__(256) void scatterL_kernel(const int* __restrict__ ei,
                                                       const float* __restrict__ ew,
                                                       const float* __restrict__ deg,
                                                       float* __restrict__ Lf) {
  int e = blockIdx.x * 256 + threadIdx.x;
  int r = ei[e], c = ei[EE + e];
  float w = (r == c) ? 0.0f : ew[e];
  float dr = deg[r], dc = deg[c];
  float ir = dr > 0.0f ? rsqrtf(dr) : 0.0f;
  float ic = dc > 0.0f ? rsqrtf(dc) : 0.0f;
  float norm = -(ir * w * ic);
  if (norm != 0.0f) atomicAdd(&Lf[(size_t)c * NN + r], norm);
}

__global__ __launch_bounds__(256) void cvtL_kernel(const float* __restrict__ Lf,
                                                   bf16* __restrict__ Lbf) {
  int i = blockIdx.x * 256 + threadIdx.x;
  Lbf[i] = (bf16)Lf[i];
}

// ------------------------------ weight prep --------------------------------
// Wc (fp32, 192x64): rows [0:64)=W0-W2, [64:128)=W1, [128:192)=2*W2
// W2c (bf16, [1152 cols][192 k]): col = og*48 + conv*16 + oo  (o = og*16+oo)
//   k = kk*64 + h ; value = w_conv[(o*64+h)*3 + kk]
__global__ __launch_bounds__(256) void wprep_kernel(const float* __restrict__ W,
                                                    const float* __restrict__ w21,
                                                    const float* __restrict__ w22,
                                                    const float* __restrict__ w23,
                                                    float* __restrict__ Wc,
                                                    bf16* __restrict__ W2c) {
  int i = blockIdx.x * 256 + threadIdx.x;   // 912*256 = 233472 = 12288 + 221184 exact
  if (i < 12288) {
    int row = i >> 6, j = i & 63;
    int src = row >> 6, h = row & 63;
    float v;
    if (src == 0)      v = W[h * 64 + j] - W[2 * 4096 + h * 64 + j];
    else if (src == 1) v = W[4096 + h * 64 + j];
    else               v = 2.0f * W[2 * 4096 + h * 64 + j];
    Wc[i] = v;
  } else {
    int j2 = i - 12288;                      // [0, 221184)
    int c = j2 / 192, k = j2 % 192;
    int og = c / 48, r48 = c % 48;
    int conv = r48 >> 4, oo = r48 & 15;
    int o = og * 16 + oo;
    int kk = k >> 6, h = k & 63;
    const float* ws = (conv == 0) ? w21 : (conv == 1) ? w22 : w23;
    W2c[j2] = (bf16)ws[(o * 64 + h) * 3 + kk];
  }
}

// ------------------------------- TC1 ---------------------------------------
// zf[(b*10+t)*64+h][n] = relu(P*sigmoid(Q)+R), feature-major bf16
__global__ __launch_bounds__(256) void tc1_kernel(const float* __restrict__ X,
                                                  const float* __restrict__ w1, const float* __restrict__ c1,
                                                  const float* __restrict__ w2, const float* __restrict__ c2,
                                                  const float* __restrict__ w3, const float* __restrict__ c3,
                                                  bf16* __restrict__ zf) {
  int row = blockIdx.y;                       // (b*10+t)*64+h, [0,10240)
  int n = blockIdx.x * 256 + threadIdx.x;
  int h = row & 63, bt = row >> 6;
  int t = bt % 10, b = bt / 10;
  float P = c1[h], Q = c2[h], R = c3[h];
  const float* xb = X + (size_t)(b * 1024 + n) * 24;   // (B,N,C=2,T=12)
  #pragma unroll
  for (int c = 0; c < 2; c++)
    #pragma unroll
    for (int k = 0; k < 3; k++) {
      float xv = xb[c * 12 + t + k];
      int wi = (h * 2 + c) * 3 + k;
      P += xv * w1[wi]; Q += xv * w2[wi]; R += xv * w3[wi];
    }
  float Hv = P * (1.0f / (1.0f + __expf(-Q))) + R;
  Hv = Hv > 0.0f ? Hv : 0.0f;
  zf[(size_t)row * NN + n] = (bf16)Hv;
}

// --------------------------- B^T GEMM (bf16) -------------------------------
// C[M][Nc] = A[M][K] * Bt[Nc][K]^T ; 128x128 tile, BK=64, global_load_lds
__global__ __launch_bounds__(256) void gemm_bt(const bf16* __restrict__ A,
                                               const bf16* __restrict__ Bt,
                                               bf16* __restrict__ C,
                                               int M, int Nc, int K) {
  __shared__ __align__(16) bf16 As[8192];
  __shared__ __align__(16) bf16 Bs[8192];
  const int tid = threadIdx.x, lane = tid & 63, w = tid >> 6;
  const int wm = w >> 1, wn = w & 1;
  const int m0 = blockIdx.y * 128, n0 = blockIdx.x * 128;
  const int colL = lane & 15, kg = lane >> 4;

  f32x4 acc[4][4];
  #pragma unroll
  for (int i = 0; i < 4; i++)
    #pragma unroll
    for (int j = 0; j < 4; j++) acc[i][j] = splat4(0.0f);

  for (int kb = 0; kb < K; kb += 64) {
    if (kb) __syncthreads();
    #pragma unroll
    for (int i = 0; i < 4; i++) {
      int e = (w * 4 + i) * 512 + lane * 8;
      int row = e >> 6, k = e & 63;
      lds_load16(&A[(size_t)(m0 + row) * K + kb + k], &As[(w * 4 + i) * 512]);
      lds_load16(&Bt[(size_t)(n0 + row) * K + kb + k], &Bs[(w * 4 + i) * 512]);
    }
    __syncthreads();
    #pragma unroll
    for (int kk = 0; kk < 2; kk++) {
      bf16x8 af[4], bfr[4];
      #pragma unroll
      for (int mt = 0; mt < 4; mt++)
        af[mt] = *(const bf16x8*)(&As[(wm * 64 + mt * 16 + colL) * 64 + kk * 32 + kg * 8]);
      #pragma unroll
      for (int nt = 0; nt < 4; nt++)
        bfr[nt] = *(const bf16x8*)(&Bs[(wn * 64 + nt * 16 + colL) * 64 + kk * 32 + kg * 8]);
      #pragma unroll
      for (int mt = 0; mt < 4; mt++)
        #pragma unroll
        for (int nt = 0; nt < 4; nt++)
          acc[mt][nt] = mfma16(af[mt], bfr[nt], acc[mt][nt]);
    }
  }
  #pragma unroll
  for (int mt = 0; mt < 4; mt++)
    #pragma unroll
    for (int nt = 0; nt < 4; nt++) {
      int m = m0 + wm * 64 + mt * 16 + kg * 4;
      int n = n0 + wn * 64 + nt * 16 + colL;
      #pragma unroll
      for (int r = 0; r < 4; r++)
        C[(size_t)(m + r) * Nc + n] = (bf16)acc[mt][nt][r];
    }
}

// ------------------------- cheb combine (vector) ---------------------------
// Tg[n][b][t][j] = relu(cheb_b[j] + sum_h z*Wc[0:64] + P1*Wc[64:128] + P2*Wc[128:192])
// Wave w owns j-quarter jg=w (16 channels) -> acc[16] in VGPRs, weights via s_load.
__global__ __launch_bounds__(256) void combine_kernel(const bf16* __restrict__ zf,
                                                      const bf16* __restrict__ P1f,
                                                      const bf16* __restrict__ P2f,
                                                      const float* __restrict__ Wc,
                                                      const float* __restrict__ chebb,
                                                      bf16* __restrict__ Tg) {
  const int slab = blockIdx.y;                 // bt in [0,160)
  const int b = slab / 10, t = slab % 10;
  const int lane = threadIdx.x & 63;
  const int jg = __builtin_amdgcn_readfirstlane(threadIdx.x >> 6);  // wave-uniform
  const int n = blockIdx.x * 64 + lane;

  float acc[16];
  #pragma unroll
  for (int j = 0; j < 16; j++) acc[j] = chebb[jg * 16 + j];

  const size_t zoff = (size_t)(slab * 64) * NN + n;
  #pragma unroll 1
  for (int src = 0; src < 3; src++) {
    const bf16* Z = (src == 0) ? zf : (src == 1) ? P1f : P2f;
    const float* wsrc = Wc + (size_t)(src * 64) * 64 + jg * 16;
    #pragma unroll 4
    for (int h = 0; h < 64; h++) {
      float v = (float)Z[zoff + (size_t)h * NN];
      const float* wr = wsrc + h * 64;         // uniform -> s_load
      #pragma unroll
      for (int j = 0; j < 16; j++) acc[j] += v * wr[j];
    }
  }

  bf16 tmp[16];
  #pragma unroll
  for (int j = 0; j < 16; j++) {
    float x = acc[j];
    tmp[j] = (bf16)(x > 0.0f ? x : 0.0f);
  }
  size_t base = (size_t)((n * 16 + b) * 10 + t) * 64 + jg * 16;
  *(bf16x8*)(&Tg[base])     = *(const bf16x8*)(&tmp[0]);
  *(bf16x8*)(&Tg[base + 8]) = *(const bf16x8*)(&tmp[8]);
}

// ----------------------- TC2 as GEMM + fused BN stats ----------------------
// C[131072 x 1152] = TgWin[131072 x 192] * W2c^T, BM=128, BN=192, BK=64.
// Col layout og*48+conv*16+oo => GLU triple (P,Q,R) is lane-local across
// three adjacent 16-col tiles. 4 waves, each 64 rows x 96 cols.
__global__ __launch_bounds__(256) void tc2_kernel(const bf16* __restrict__ Tg,
                                                  const bf16* __restrict__ W2c,
                                                  const float* __restrict__ b1,
                                                  const float* __restrict__ b2,
                                                  const float* __restrict__ b3,
                                                  float* __restrict__ nsum,
                                                  float* __restrict__ nsq,
                                                  bf16* __restrict__ slice) {
  __shared__ __align__(16) char smem[40960];
  bf16* As = (bf16*)smem;                 // [128][64]  16 KB
  bf16* Ws = (bf16*)(smem + 16384);       // [192][64]  24 KB
  const int rb = blockIdx.x, cho = blockIdx.y;
  const int b = rb >> 6, tpp = (rb >> 3) & 7, n0 = (rb & 7) << 7;
  const int tid = threadIdx.x, lane = tid & 63, w = tid >> 6;
  const int wm = w >> 1, wn = w & 1;
  const int colL = lane & 15, kg = lane >> 4;

  f32x4 acc[4][6];
  #pragma unroll
  for (int i = 0; i < 4; i++)
    #pragma unroll
    for (int j = 0; j < 6; j++) acc[i][j] = splat4(0.0f);

  for (int kb = 0; kb < 192; kb += 64) {
    if (kb) __syncthreads();
    #pragma unroll
    for (int i = 0; i < 4; i++) {          // A: 128x64
      int e = (w * 4 + i) * 512 + lane * 8;
      int row = e >> 6, k = e & 63;
      lds_load16(&Tg[(size_t)((n0 + row) * 16 + b) * 640 + tpp * 64 + kb + k],
                 &As[(w * 4 + i) * 512]);
    }
    #pragma unroll
    for (int i = 0; i < 6; i++) {          // W: 192x64
      int e = (w * 6 + i) * 512 + lane * 8;
      int col = e >> 6, k = e & 63;
      lds_load16(&W2c[(size_t)(cho * 192 + col) * 192 + kb + k],
                 &Ws[(w * 6 + i) * 512]);
    }
    __syncthreads();
    #pragma unroll
    for (int kk = 0; kk < 2; kk++) {
      bf16x8 af[4], bfr[6];
      #pragma unroll
      for (int mt = 0; mt < 4; mt++)
        af[mt] = *(const bf16x8*)(&As[(wm * 64 + mt * 16 + colL) * 64 + kk * 32 + kg * 8]);
      #pragma unroll
      for (int j = 0; j < 6; j++)
        bfr[j] = *(const bf16x8*)(&Ws[(wn * 96 + j * 16 + colL) * 64 + kk * 32 + kg * 8]);
      #pragma unroll
      for (int mt = 0; mt < 4; mt++)
        #pragma unroll
        for (int j = 0; j < 6; j++)
          acc[mt][j] = mfma16(af[mt], bfr[j], acc[mt][j]);
    }
  }

  // GLU epilogue + per-row stats
  float ssum[4][4], ssq[4][4];
  #pragma unroll
  for (int mt = 0; mt < 4; mt++)
    #pragma unroll
    for (int r = 0; r < 4; r++) { ssum[mt][r] = 0.0f; ssq[mt][r] = 0.0f; }

  float bv1[2], bv2[2], bv3[2];
  int obase[2];
  #pragma unroll
  for (int g = 0; g < 2; g++) {
    int o = ((cho * 4 + wn * 2 + g) << 4) + colL;
    obase[g] = o;
    bv1[g] = b1[o]; bv2[g] = b2[o]; bv3[g] = b3[o];
  }

  #pragma unroll
  for (int mt = 0; mt < 4; mt++)
    #pragma unroll
    for (int g = 0; g < 2; g++) {
      int o = obase[g];
      #pragma unroll
      for (int r = 0; r < 4; r++) {
        float p  = acc[mt][g * 3 + 0][r] + bv1[g];
        float q  = acc[mt][g * 3 + 1][r] + bv2[g];
        float rr = acc[mt][g * 3 + 2][r] + bv3[g];
        float h = p * (1.0f / (1.0f + __expf(-q))) + rr;
        h = h > 0.0f ? h : 0.0f;
        ssum[mt][r] += h;
        ssq[mt][r] += h * h;
        if (tpp == 7) {
          int n = n0 + wm * 64 + mt * 16 + kg * 4 + r;
          slice[(size_t)((b << 10) + n) * 384 + o] = (bf16)h;
        }
      }
    }

  // reduce over colL (16 lanes), then LDS, then 2 atomics per row
  __syncthreads();                          // all LDS reads done; alias smem
  float* sred = (float*)smem;               // [128][2]
  if (tid < 256) { sred[tid] = 0.0f; }
  __syncthreads();
  #pragma unroll
  for (int mt = 0; mt < 4; mt++)
    #pragma unroll
    for (int r = 0; r < 4; r++) {
      float s = ssum[mt][r], q = ssq[mt][r];
      #pragma unroll
      for (int d = 1; d < 16; d <<= 1) {
        s += __shfl_xor(s, d);
        q += __shfl_xor(q, d);
      }
      if (colL == 0) {
        int rl = wm * 64 + mt * 16 + kg * 4 + r;   // local row [0,128)
        atomicAdd(&sred[rl * 2], s);
        atomicAdd(&sred[rl * 2 + 1], q);
      }
    }
  __syncthreads();
  if (tid < 128) {
    atomicAdd(&nsum[n0 + tid], sred[tid * 2]);
    atomicAdd(&nsq[n0 + tid], sred[tid * 2 + 1]);
  }
}

// ----------------------------- BN finalize ---------------------------------
__global__ __launch_bounds__(256) void bnstat_kernel(const float* __restrict__ nsum,
                                                     const float* __restrict__ nsq,
                                                     const float* __restrict__ gamma,
                                                     const float* __restrict__ beta,
                                                     float* __restrict__ scoff) {
  int n = blockIdx.x * 256 + threadIdx.x;       // 1024 exact
  const float inv_cnt = 1.0f / 49152.0f;        // B*8*384
  float m = nsum[n] * inv_cnt;
  float var = nsq[n] * inv_cnt - m * m;
  float sc = rsqrtf(var + 1e-5f) * gamma[n];
  scoff[n] = sc;
  scoff[1024 + n] = beta[n] - m * sc;
}

// out[f], f = c*16384 + b*1024 + n  (== reshape(T,B,N,OUT) flat order)
__global__ __launch_bounds__(256) void final_kernel(const bf16* __restrict__ slice,
                                                    const float* __restrict__ scoff,
                                                    float* __restrict__ out) {
  int f = blockIdx.x * 256 + threadIdx.x;       // 6291456 exact
  int c = f >> 14, rem = f & 16383;
  int b = rem >> 10, n = rem & 1023;
  out[f] = (float)slice[(size_t)((b << 10) + n) * 384 + c] * scoff[n] + scoff[1024 + n];
}

// ---------------------------------------------------------------------------
extern "C" void kernel_launch(void* const* d_in, const int* in_sizes, int n_in,
                              void* d_out, int out_size, void* d_ws, size_t ws_size,
                              hipStream_t stream) {
  const float* X    = (const float*)d_in[0];
  const int*   ei   = (const int*)d_in[1];
  const float* ew   = (const float*)d_in[2];
  const float* t1w1 = (const float*)d_in[3];
  const float* t1b1 = (const float*)d_in[4];
  const float* t1w2 = (const float*)d_in[5];
  const float* t1b2 = (const float*)d_in[6];
  const float* t1w3 = (const float*)d_in[7];
  const float* t1b3 = (const float*)d_in[8];
  const float* chebW = (const float*)d_in[9];
  const float* chebB = (const float*)d_in[10];
  const float* t2w1 = (const float*)d_in[11];
  const float* t2b1 = (const float*)d_in[12];
  const float* t2w2 = (const float*)d_in[13];
  const float* t2b2 = (const float*)d_in[14];
  const float* t2w3 = (const float*)d_in[15];
  const float* t2b3 = (const float*)d_in[16];
  const float* gamma = (const float*)d_in[17];
  const float* beta  = (const float*)d_in[18];
  float* out = (float*)d_out;

  char* ws = (char*)d_ws;
  float* Lf    = (float*)(ws);                  // 4 MB dense L (fp32 scatter target)
  float* deg   = (float*)(ws + 4194304);
  float* nsum  = (float*)(ws + 4198400);
  float* nsq   = (float*)(ws + 4202496);
  bf16*  Lbf   = (bf16*)(ws + 4210688);         // 2 MB
  bf16*  zf    = (bf16*)(ws + 6307840);         // 20 MB feature-major z
  bf16*  P1f   = (bf16*)(ws + 27279360);        // 20 MB
  bf16*  P2f   = (bf16*)(ws + 48250880);        // 20 MB
  bf16*  Tg    = (bf16*)(ws + 69222400);        // 20 MB node-major
  float* Wc    = (float*)(ws + 90193920);       // 48 KB combined cheb weights
  bf16*  W2c   = (bf16*)(ws + 90243072);        // 432 KB tc2 weights [col][k]
  bf16*  slice = (bf16*)(ws + 90685440);        // 12 MB t''=7 slice
  float* scoff = (float*)(ws + 103268352);      // 8 KB

  hipMemsetAsync(ws, 0, 4206592, stream);       // Lf + deg + nsum + nsq

  wprep_kernel<<<912, 256, 0, stream>>>(chebW, t2w1, t2w2, t2w3, Wc, W2c);
  tc1_kernel<<<dim3(4, 10240), 256, 0, stream>>>(X, t1w1, t1b1, t1w2, t1b2, t1w3, t1b3, zf);
  deg_kernel<<<64, 256, 0, stream>>>(ei, ew, deg);
  scatterL_kernel<<<64, 256, 0, stream>>>(ei, ew, deg, Lf);
  cvtL_kernel<<<4096, 256, 0, stream>>>(Lf, Lbf);
  gemm_bt<<<dim3(8, 80), 256, 0, stream>>>(zf, Lbf, P1f, 10240, 1024, 1024);
  gemm_bt<<<dim3(8, 80), 256, 0, stream>>>(P1f, Lbf, P2f, 10240, 1024, 1024);
  combine_kernel<<<dim3(16, 160), 256, 0, stream>>>(zf, P1f, P2f, Wc, chebB, Tg);
  tc2_kernel<<<dim3(1024, 6), 256, 0, stream>>>(Tg, W2c, t2b1, t2b2, t2b3, nsum, nsq, slice);
  bnstat_kernel<<<4, 256, 0, stream>>>(nsum, nsq, gamma, beta, scoff);
  final_kernel<<<24576, 256, 0, stream>>>(slice, scoff, out);
}

// Round 5
// 391.479 us; speedup vs baseline: 1.7058x; 1.0659x over previous
//
#include <hip/hip_runtime.h>

// ---------------------------------------------------------------------------
// STGCN forward, MI355X. Internal compute bf16-MFMA / fp32-accum.
// TC1 -> (dense-L build) -> prop GEMM x2 -> cheb combine -> TC2-as-GEMM+stats
// -> BN finalize. T2 never materialized (only per-node stats + t''=7 slice).
// LDS tiles use XOR slot-swizzle (pre-swizzled global source, swizzled read)
// to kill the 16-way ds_read_b128 bank conflict at 128B row stride.
// ---------------------------------------------------------------------------

typedef __bf16 bf16;
typedef __bf16 bf16x8 __attribute__((ext_vector_type(8)));
typedef float  f32x4  __attribute__((ext_vector_type(4)));

__device__ __forceinline__ f32x4 mfma16(bf16x8 a, bf16x8 b, f32x4 c) {
  return __builtin_amdgcn_mfma_f32_16x16x32_bf16(a, b, c, 0, 0, 0);
}
__device__ __forceinline__ f32x4 splat4(float v) { f32x4 t = {v, v, v, v}; return t; }

// async global->LDS, 16B per lane; lds base must be wave-uniform (lane*16 auto)
__device__ __forceinline__ void lds_load16(const bf16* g, bf16* l) {
  __builtin_amdgcn_global_load_lds((const __attribute__((address_space(1))) void*)g,
                                   (__attribute__((address_space(3))) void*)l, 16, 0, 0);
}

#define NN 1024
#define EE 16384

// --------------------------- edge preprocessing ----------------------------
__global__ __launch_bounds__(256) void deg_kernel(const int* __restrict__ ei,
                                                  const float* __restrict__ ew,
                                                  float* __restrict__ deg) {
  int e = blockIdx.x * 256 + threadIdx.x;
  int r = ei[e], c = ei[EE + e];
  if (r != c) atomicAdd(&deg[r], ew[e]);
}

// L[col][row] += -dinv[row]*w*dinv[col]  (dense 1024x1024 fp32)
__global__ __launch_bounds__(256) void scatterL_kernel(const int* __restrict__ ei,
                                                       const float* __restrict__ ew,
                                                       const float* __restrict__ deg,
                                                       float* __restrict__ Lf) {
  int e = blockIdx.x * 256 + threadIdx.x;
  int r = ei[e], c = ei[EE + e];
  float w = (r == c) ? 0.0f : ew[e];
  float dr = deg[r], dc = deg[c];
  float ir = dr > 0.0f ? rsqrtf(dr) : 0.0f;
  float ic = dc > 0.0f ? rsqrtf(dc) : 0.0f;
  float norm = -(ir * w * ic);
  if (norm != 0.0f) atomicAdd(&Lf[(size_t)c * NN + r], norm);
}

__global__ __launch_bounds__(256) void cvtL_kernel(const float* __restrict__ Lf,
                                                   bf16* __restrict__ Lbf) {
  int i = blockIdx.x * 256 + threadIdx.x;
  Lbf[i] = (bf16)Lf[i];
}

// ------------------------------ weight prep --------------------------------
// Wc (fp32, 192x64): rows [0:64)=W0-W2, [64:128)=W1, [128:192)=2*W2
// W2c (bf16, [1152 cols][192 k]): col = og*48 + conv*16 + oo  (o = og*16+oo)
//   k = kk*64 + h ; value = w_conv[(o*64+h)*3 + kk]
__global__ __launch_bounds__(256) void wprep_kernel(const float* __restrict__ W,
                                                    const float* __restrict__ w21,
                                                    const float* __restrict__ w22,
                                                    const float* __restrict__ w23,
                                                    float* __restrict__ Wc,
                                                    bf16* __restrict__ W2c) {
  int i = blockIdx.x * 256 + threadIdx.x;   // 912*256 = 233472 = 12288 + 221184 exact
  if (i < 12288) {
    int row = i >> 6, j = i & 63;
    int src = row >> 6, h = row & 63;
    float v;
    if (src == 0)      v = W[h * 64 + j] - W[2 * 4096 + h * 64 + j];
    else if (src == 1) v = W[4096 + h * 64 + j];
    else               v = 2.0f * W[2 * 4096 + h * 64 + j];
    Wc[i] = v;
  } else {
    int j2 = i - 12288;                      // [0, 221184)
    int c = j2 / 192, k = j2 % 192;
    int og = c / 48, r48 = c % 48;
    int conv = r48 >> 4, oo = r48 & 15;
    int o = og * 16 + oo;
    int kk = k >> 6, h = k & 63;
    const float* ws = (conv == 0) ? w21 : (conv == 1) ? w22 : w23;
    W2c[j2] = (bf16)ws[(o * 64 + h) * 3 + kk];
  }
}

// ------------------------------- TC1 ---------------------------------------
// zf[(b*10+t)*64+h][n] = relu(P*sigmoid(Q)+R), feature-major bf16
__global__ __launch_bounds__(256) void tc1_kernel(const float* __restrict__ X,
                                                  const float* __restrict__ w1, const float* __restrict__ c1,
                                                  const float* __restrict__ w2, const float* __restrict__ c2,
                                                  const float* __restrict__ w3, const float* __restrict__ c3,
                                                  bf16* __restrict__ zf) {
  int row = blockIdx.y;                       // (b*10+t)*64+h, [0,10240)
  int n = blockIdx.x * 256 + threadIdx.x;
  int h = row & 63, bt = row >> 6;
  int t = bt % 10, b = bt / 10;
  float P = c1[h], Q = c2[h], R = c3[h];
  const float* xb = X + (size_t)(b * 1024 + n) * 24;   // (B,N,C=2,T=12)
  #pragma unroll
  for (int c = 0; c < 2; c++)
    #pragma unroll
    for (int k = 0; k < 3; k++) {
      float xv = xb[c * 12 + t + k];
      int wi = (h * 2 + c) * 3 + k;
      P += xv * w1[wi]; Q += xv * w2[wi]; R += xv * w3[wi];
    }
  float Hv = P * (1.0f / (1.0f + __expf(-Q))) + R;
  Hv = Hv > 0.0f ? Hv : 0.0f;
  zf[(size_t)row * NN + n] = (bf16)Hv;
}

// --------------------------- B^T GEMM (bf16) -------------------------------
// C[M][Nc] = A[M][K] * Bt[Nc][K]^T ; 128x128 tile, BK=64, global_load_lds.
// LDS rows of 64 bf16 = 8 slots of 16B; physical slot = logical ^ (row&7).
__global__ __launch_bounds__(256) void gemm_bt(const bf16* __restrict__ A,
                                               const bf16* __restrict__ Bt,
                                               bf16* __restrict__ C,
                                               int M, int Nc, int K) {
  __shared__ __align__(16) bf16 As[8192];
  __shared__ __align__(16) bf16 Bs[8192];
  const int tid = threadIdx.x, lane = tid & 63, w = tid >> 6;
  const int wm = w >> 1, wn = w & 1;
  const int m0 = blockIdx.y * 128, n0 = blockIdx.x * 128;
  const int colL = lane & 15, kg = lane >> 4;
  const int rxor = colL & 7;                 // row&7 for all fragment rows

  f32x4 acc[4][4];
  #pragma unroll
  for (int i = 0; i < 4; i++)
    #pragma unroll
    for (int j = 0; j < 4; j++) acc[i][j] = splat4(0.0f);

  for (int kb = 0; kb < K; kb += 64) {
    if (kb) __syncthreads();
    #pragma unroll
    for (int i = 0; i < 4; i++) {
      int e = (w * 4 + i) * 512 + lane * 8;
      int row = e >> 6, s = (e >> 3) & 7;
      int ksw = ((s ^ (row & 7)) << 3);      // pre-swizzled source slot
      lds_load16(&A[(size_t)(m0 + row) * K + kb + ksw], &As[(w * 4 + i) * 512]);
      lds_load16(&Bt[(size_t)(n0 + row) * K + kb + ksw], &Bs[(w * 4 + i) * 512]);
    }
    __syncthreads();
    #pragma unroll
    for (int kk = 0; kk < 2; kk++) {
      bf16x8 af[4], bfr[4];
      #pragma unroll
      for (int mt = 0; mt < 4; mt++)
        af[mt] = *(const bf16x8*)(&As[(wm * 64 + mt * 16 + colL) * 64 +
                                      (((kk * 4 + kg) ^ rxor) << 3)]);
      #pragma unroll
      for (int nt = 0; nt < 4; nt++)
        bfr[nt] = *(const bf16x8*)(&Bs[(wn * 64 + nt * 16 + colL) * 64 +
                                       (((kk * 4 + kg) ^ rxor) << 3)]);
      #pragma unroll
      for (int mt = 0; mt < 4; mt++)
        #pragma unroll
        for (int nt = 0; nt < 4; nt++)
          acc[mt][nt] = mfma16(af[mt], bfr[nt], acc[mt][nt]);
    }
  }
  #pragma unroll
  for (int mt = 0; mt < 4; mt++)
    #pragma unroll
    for (int nt = 0; nt < 4; nt++) {
      int m = m0 + wm * 64 + mt * 16 + kg * 4;
      int n = n0 + wn * 64 + nt * 16 + colL;
      #pragma unroll
      for (int r = 0; r < 4; r++)
        C[(size_t)(m + r) * Nc + n] = (bf16)acc[mt][nt][r];
    }
}

// ------------------------- cheb combine (vector) ---------------------------
// Tg[n][b][t][j] = relu(cheb_b[j] + sum_h z*Wc[0:64] + P1*Wc[64:128] + P2*Wc[128:192])
// Wave w owns j-quarter jg=w (16 channels) -> acc[16] in VGPRs, weights via s_load.
__global__ __launch_bounds__(256) void combine_kernel(const bf16* __restrict__ zf,
                                                      const bf16* __restrict__ P1f,
                                                      const bf16* __restrict__ P2f,
                                                      const float* __restrict__ Wc,
                                                      const float* __restrict__ chebb,
                                                      bf16* __restrict__ Tg) {
  const int slab = blockIdx.y;                 // bt in [0,160)
  const int b = slab / 10, t = slab % 10;
  const int lane = threadIdx.x & 63;
  const int jg = __builtin_amdgcn_readfirstlane(threadIdx.x >> 6);  // wave-uniform
  const int n = blockIdx.x * 64 + lane;

  float acc[16];
  #pragma unroll
  for (int j = 0; j < 16; j++) acc[j] = chebb[jg * 16 + j];

  const size_t zoff = (size_t)(slab * 64) * NN + n;
  #pragma unroll 1
  for (int src = 0; src < 3; src++) {
    const bf16* Z = (src == 0) ? zf : (src == 1) ? P1f : P2f;
    const float* wsrc = Wc + (size_t)(src * 64) * 64 + jg * 16;
    #pragma unroll 4
    for (int h = 0; h < 64; h++) {
      float v = (float)Z[zoff + (size_t)h * NN];
      const float* wr = wsrc + h * 64;         // uniform -> s_load
      #pragma unroll
      for (int j = 0; j < 16; j++) acc[j] += v * wr[j];
    }
  }

  bf16 tmp[16];
  #pragma unroll
  for (int j = 0; j < 16; j++) {
    float x = acc[j];
    tmp[j] = (bf16)(x > 0.0f ? x : 0.0f);
  }
  size_t base = (size_t)((n * 16 + b) * 10 + t) * 64 + jg * 16;
  *(bf16x8*)(&Tg[base])     = *(const bf16x8*)(&tmp[0]);
  *(bf16x8*)(&Tg[base + 8]) = *(const bf16x8*)(&tmp[8]);
}

// ----------------------- TC2 as GEMM + fused BN stats ----------------------
// C[131072 x 1152] = TgWin[131072 x 192] * W2c^T, BM=128, BN=192, BK=64.
// Col layout og*48+conv*16+oo => GLU triple (P,Q,R) is lane-local across
// three adjacent 16-col tiles. 4 waves, each 64 rows x 96 cols.
// Same XOR slot-swizzle as gemm_bt on As and Ws.
__global__ __launch_bounds__(256) void tc2_kernel(const bf16* __restrict__ Tg,
                                                  const bf16* __restrict__ W2c,
                                                  const float* __restrict__ b1,
                                                  const float* __restrict__ b2,
                                                  const float* __restrict__ b3,
                                                  float* __restrict__ nsum,
                                                  float* __restrict__ nsq,
                                                  bf16* __restrict__ slice) {
  __shared__ __align__(16) char smem[40960];
  bf16* As = (bf16*)smem;                 // [128][64]  16 KB
  bf16* Ws = (bf16*)(smem + 16384);       // [192][64]  24 KB
  const int rb = blockIdx.x, cho = blockIdx.y;
  const int b = rb >> 6, tpp = (rb >> 3) & 7, n0 = (rb & 7) << 7;
  const int tid = threadIdx.x, lane = tid & 63, w = tid >> 6;
  const int wm = w >> 1, wn = w & 1;
  const int colL = lane & 15, kg = lane >> 4;
  const int rxor = colL & 7;

  f32x4 acc[4][6];
  #pragma unroll
  for (int i = 0; i < 4; i++)
    #pragma unroll
    for (int j = 0; j < 6; j++) acc[i][j] = splat4(0.0f);

  for (int kb = 0; kb < 192; kb += 64) {
    if (kb) __syncthreads();
    #pragma unroll
    for (int i = 0; i < 4; i++) {          // A: 128x64
      int e = (w * 4 + i) * 512 + lane * 8;
      int row = e >> 6, s = (e >> 3) & 7;
      int ksw = ((s ^ (row & 7)) << 3);
      lds_load16(&Tg[(size_t)((n0 + row) * 16 + b) * 640 + tpp * 64 + kb + ksw],
                 &As[(w * 4 + i) * 512]);
    }
    #pragma unroll
    for (int i = 0; i < 6; i++) {          // W: 192x64
      int e = (w * 6 + i) * 512 + lane * 8;
      int col = e >> 6, s = (e >> 3) & 7;
      int ksw = ((s ^ (col & 7)) << 3);
      lds_load16(&W2c[(size_t)(cho * 192 + col) * 192 + kb + ksw],
                 &Ws[(w * 6 + i) * 512]);
    }
    __syncthreads();
    #pragma unroll
    for (int kk = 0; kk < 2; kk++) {
      bf16x8 af[4], bfr[6];
      #pragma unroll
      for (int mt = 0; mt < 4; mt++)
        af[mt] = *(const bf16x8*)(&As[(wm * 64 + mt * 16 + colL) * 64 +
                                      (((kk * 4 + kg) ^ rxor) << 3)]);
      #pragma unroll
      for (int j = 0; j < 6; j++)
        bfr[j] = *(const bf16x8*)(&Ws[(wn * 96 + j * 16 + colL) * 64 +
                                      (((kk * 4 + kg) ^ rxor) << 3)]);
      #pragma unroll
      for (int mt = 0; mt < 4; mt++)
        #pragma unroll
        for (int j = 0; j < 6; j++)
          acc[mt][j] = mfma16(af[mt], bfr[j], acc[mt][j]);
    }
  }

  // GLU epilogue + per-row stats
  float ssum[4][4], ssq[4][4];
  #pragma unroll
  for (int mt = 0; mt < 4; mt++)
    #pragma unroll
    for (int r = 0; r < 4; r++) { ssum[mt][r] = 0.0f; ssq[mt][r] = 0.0f; }

  float bv1[2], bv2[2], bv3[2];
  int obase[2];
  #pragma unroll
  for (int g = 0; g < 2; g++) {
    int o = ((cho * 4 + wn * 2 + g) << 4) + colL;
    obase[g] = o;
    bv1[g] = b1[o]; bv2[g] = b2[o]; bv3[g] = b3[o];
  }

  #pragma unroll
  for (int mt = 0; mt < 4; mt++)
    #pragma unroll
    for (int g = 0; g < 2; g++) {
      int o = obase[g];
      #pragma unroll
      for (int r = 0; r < 4; r++) {
        float p  = acc[mt][g * 3 + 0][r] + bv1[g];
        float q  = acc[mt][g * 3 + 1][r] + bv2[g];
        float rr = acc[mt][g * 3 + 2][r] + bv3[g];
        float h = p * (1.0f / (1.0f + __expf(-q))) + rr;
        h = h > 0.0f ? h : 0.0f;
        ssum[mt][r] += h;
        ssq[mt][r] += h * h;
        if (tpp == 7) {
          int n = n0 + wm * 64 + mt * 16 + kg * 4 + r;
          slice[(size_t)((b << 10) + n) * 384 + o] = (bf16)h;
        }
      }
    }

  // reduce over colL (16 lanes), then LDS, then 2 atomics per row
  __syncthreads();                          // all LDS reads done; alias smem
  float* sred = (float*)smem;               // [128][2]
  if (tid < 256) { sred[tid] = 0.0f; }
  __syncthreads();
  #pragma unroll
  for (int mt = 0; mt < 4; mt++)
    #pragma unroll
    for (int r = 0; r < 4; r++) {
      float s = ssum[mt][r], q = ssq[mt][r];
      #pragma unroll
      for (int d = 1; d < 16; d <<= 1) {
        s += __shfl_xor(s, d);
        q += __shfl_xor(q, d);
      }
      if (colL == 0) {
        int rl = wm * 64 + mt * 16 + kg * 4 + r;   // local row [0,128)
        atomicAdd(&sred[rl * 2], s);
        atomicAdd(&sred[rl * 2 + 1], q);
      }
    }
  __syncthreads();
  if (tid < 128) {
    atomicAdd(&nsum[n0 + tid], sred[tid * 2]);
    atomicAdd(&nsq[n0 + tid], sred[tid * 2 + 1]);
  }
}

// ----------------------------- BN finalize ---------------------------------
__global__ __launch_bounds__(256) void bnstat_kernel(const float* __restrict__ nsum,
                                                     const float* __restrict__ nsq,
                                                     const float* __restrict__ gamma,
                                                     const float* __restrict__ beta,
                                                     float* __restrict__ scoff) {
  int n = blockIdx.x * 256 + threadIdx.x;       // 1024 exact
  const float inv_cnt = 1.0f / 49152.0f;        // B*8*384
  float m = nsum[n] * inv_cnt;
  float var = nsq[n] * inv_cnt - m * m;
  float sc = rsqrtf(var + 1e-5f) * gamma[n];
  scoff[n] = sc;
  scoff[1024 + n] = beta[n] - m * sc;
}

// out[f], f = c*16384 + b*1024 + n  (== reshape(T,B,N,OUT) flat order)
__global__ __launch_bounds__(256) void final_kernel(const bf16* __restrict__ slice,
                                                    const float* __restrict__ scoff,
                                                    float* __restrict__ out) {
  int f = blockIdx.x * 256 + threadIdx.x;       // 6291456 exact
  int c = f >> 14, rem = f & 16383;
  int b = rem >> 10, n = rem & 1023;
  out[f] = (float)slice[(size_t)((b << 10) + n) * 384 + c] * scoff[n] + scoff[1024 + n];
}

// ---------------------------------------------------------------------------
extern "C" void kernel_launch(void* const* d_in, const int* in_sizes, int n_in,
                              void* d_out, int out_size, void* d_ws, size_t ws_size,
                              hipStream_t stream) {
  const float* X    = (const float*)d_in[0];
  const int*   ei   = (const int*)d_in[1];
  const float* ew   = (const float*)d_in[2];
  const float* t1w1 = (const float*)d_in[3];
  const float* t1b1 = (const float*)d_in[4];
  const float* t1w2 = (const float*)d_in[5];
  const float* t1b2 = (const float*)d_in[6];
  const float* t1w3 = (const float*)d_in[7];
  const float* t1b3 = (const float*)d_in[8];
  const float* chebW = (const float*)d_in[9];
  const float* chebB = (const float*)d_in[10];
  const float* t2w1 = (const float*)d_in[11];
  const float* t2b1 = (const float*)d_in[12];
  const float* t2w2 = (const float*)d_in[13];
  const float* t2b2 = (const float*)d_in[14];
  const float* t2w3 = (const float*)d_in[15];
  const float* t2b3 = (const float*)d_in[16];
  const float* gamma = (const float*)d_in[17];
  const float* beta  = (const float*)d_in[18];
  float* out = (float*)d_out;

  char* ws = (char*)d_ws;
  float* Lf    = (float*)(ws);                  // 4 MB dense L (fp32 scatter target)
  float* deg   = (float*)(ws + 4194304);
  float* nsum  = (float*)(ws + 4198400);
  float* nsq   = (float*)(ws + 4202496);
  bf16*  Lbf   = (bf16*)(ws + 4210688);         // 2 MB
  bf16*  zf    = (bf16*)(ws + 6307840);         // 20 MB feature-major z
  bf16*  P1f   = (bf16*)(ws + 27279360);        // 20 MB
  bf16*  P2f   = (bf16*)(ws + 48250880);        // 20 MB
  bf16*  Tg    = (bf16*)(ws + 69222400);        // 20 MB node-major
  float* Wc    = (float*)(ws + 90193920);       // 48 KB combined cheb weights
  bf16*  W2c   = (bf16*)(ws + 90243072);        // 432 KB tc2 weights [col][k]
  bf16*  slice = (bf16*)(ws + 90685440);        // 12 MB t''=7 slice
  float* scoff = (float*)(ws + 103268352);      // 8 KB

  hipMemsetAsync(ws, 0, 4206592, stream);       // Lf + deg + nsum + nsq

  wprep_kernel<<<912, 256, 0, stream>>>(chebW, t2w1, t2w2, t2w3, Wc, W2c);
  tc1_kernel<<<dim3(4, 10240), 256, 0, stream>>>(X, t1w1, t1b1, t1w2, t1b2, t1w3, t1b3, zf);
  deg_kernel<<<64, 256, 0, stream>>>(ei, ew, deg);
  scatterL_kernel<<<64, 256, 0, stream>>>(ei, ew, deg, Lf);
  cvtL_kernel<<<4096, 256, 0, stream>>>(Lf, Lbf);
  gemm_bt<<<dim3(8, 80), 256, 0, stream>>>(zf, Lbf, P1f, 10240, 1024, 1024);
  gemm_bt<<<dim3(8, 80), 256, 0, stream>>>(P1f, Lbf, P2f, 10240, 1024, 1024);
  combine_kernel<<<dim3(16, 160), 256, 0, stream>>>(zf, P1f, P2f, Wc, chebB, Tg);
  tc2_kernel<<<dim3(1024, 6), 256, 0, stream>>>(Tg, W2c, t2b1, t2b2, t2b3, nsum, nsq, slice);
  bnstat_kernel<<<4, 256, 0, stream>>>(nsum, nsq, gamma, beta, scoff);
  final_kernel<<<24576, 256, 0, stream>>>(slice, scoff, out);
}